// Round 7
// baseline (74.170 us; speedup 1.0000x reference)
//
#include <hip/hip_runtime.h>
#include <hip/hip_bf16.h>

typedef __attribute__((ext_vector_type(8))) short short8;
typedef __attribute__((ext_vector_type(4))) float f32x4;
typedef __attribute__((ext_vector_type(4))) unsigned int u32x4;

#define WS_X1_OFF 0u
#define WS_WE_OFF 262144u   // 2048*64*2 bytes of x1 bf16
#define WS_WN_OFF 278528u   // + 16*64*8*2 bytes of w_e2e frags
#define MFMA(a,b,c) __builtin_amdgcn_mfma_f32_16x16x32_bf16(a,b,c,0,0,0)

__device__ __forceinline__ short f2bs(float f) {
  __hip_bfloat16 h = __float2bfloat16(f);   // HW RNE cvt
  return *reinterpret_cast<short*>(&h);
}
__device__ __forceinline__ short8 cvt8(float4 a, float4 b) {
  short8 t;
  t[0]=f2bs(a.x); t[1]=f2bs(a.y); t[2]=f2bs(a.z); t[3]=f2bs(a.w);
  t[4]=f2bs(b.x); t[5]=f2bs(b.y); t[6]=f2bs(b.z); t[7]=f2bs(b.w);
  return t;
}
__device__ __forceinline__ short8 mask8(short8 v, unsigned int m) {
  u32x4 u; __builtin_memcpy(&u, &v, 16);
  u[0]&=m; u[1]&=m; u[2]&=m; u[3]&=m;
  short8 t; __builtin_memcpy(&t, &u, 16);
  return t;
}

// ---------------- setup kernel: x1 = relu(x@w_n2e+b) as bf16; weight frags ----
__global__ __launch_bounds__(256) void gnn_pre(
    const float* __restrict__ x, const float* __restrict__ w_n2e,
    const float* __restrict__ b_n2e, const float* __restrict__ w_e2e,
    const float* __restrict__ w_e2n, unsigned short* __restrict__ x1ws,
    unsigned short* __restrict__ wEf, unsigned short* __restrict__ wNf)
{
  int blk = blockIdx.x, tid = threadIdx.x;
  if (blk < 512) {                       // x1: 2048 rows x 64 feats
    int idx = blk * 256 + tid;
    int row = idx >> 6, f = idx & 63;
    float s = b_n2e[f];
    const float* xr = x + (size_t)row * 64;
    #pragma unroll 8
    for (int k = 0; k < 64; k++) s += xr[k] * w_n2e[k * 64 + f];
    x1ws[idx] = (unsigned short)f2bs(fmaxf(s, 0.f));
  } else if (blk < 516) {                // w_e2e -> 16 B-frags (ks0..3, n0..3)
    int t = (blk - 512) * 256 + tid;
    int frag = t >> 6, lane = t & 63;
    int ks = frag >> 2, n = frag & 3, g = lane >> 4, r = lane & 15;
    unsigned short* dst = wEf + frag * 512 + lane * 8;
    #pragma unroll
    for (int e = 0; e < 8; e++)
      dst[e] = (unsigned short)f2bs(w_e2e[(ks * 32 + g * 8 + e) * 64 + n * 16 + r]);
  } else {                               // w_e2n -> 8 B-frags (ks0..1, n0..3)
    int t = (blk - 516) * 256 + tid;
    int frag = t >> 6, lane = t & 63;
    int ks = frag >> 2, n = frag & 3, g = lane >> 4, r = lane & 15;
    unsigned short* dst = wNf + frag * 512 + lane * 8;
    #pragma unroll
    for (int e = 0; e < 8; e++)
      dst[e] = (unsigned short)f2bs(w_e2n[(ks * 32 + g * 8 + e) * 64 + n * 16 + r]);
  }
}

// ---------------- main fused kernel -------------------------------------------
// 512 threads = 8 waves x 32 output rows (R5 wave shape: acc[2][4]=32 AGPR,
// W stage 32 VGPR). Each block runs 4 consecutive (b,i) tiles with REGISTER
// prefetch: tile t+1's W loads issue right after tile t's fragments convert,
// staying in flight under tile t's GEMMs. x1/biases/frag loads amortized x4.
// launch_bounds(512,2): ~150 VGPR peak, far from 256 cap -> NO spills
// (R2/R4 lesson: spills show as FETCH/WRITE inflation; check counters).
// Occupancy proven non-binding (R5), so 1 block/CU is acceptable.
__global__ __launch_bounds__(512, 2) void gnn_main(
    const float* __restrict__ A, const float* __restrict__ W,
    const float* __restrict__ x,
    const float* __restrict__ b_e2e, const float* __restrict__ b_e2n,
    const float* __restrict__ w_n2n, const float* __restrict__ b_n2n,
    const unsigned short* __restrict__ x1ws,
    const unsigned short* __restrict__ wEf,
    const unsigned short* __restrict__ wNf,
    float* __restrict__ out)
{
  __shared__ __align__(16) float Arow[2][8][256];  // ping-pong per tile, wave-private rows
  __shared__ float x2s[4][8][64];                  // per-tile partials
  __shared__ __align__(16) char wn[8][4096];       // per-wave 32x64 bf16 W_new tile

  const int tid = threadIdx.x;
  const int w = tid >> 6, l = tid & 63, g = l >> 4, r = l & 15;
  const size_t bi0 = (size_t)blockIdx.x * 4;       // 4 tiles, same b (256%4==0)
  const int b = (int)(bi0 >> 8);
  const int j0 = w * 32;
  char* wnw = &wn[w][0];

  float4 wreg[2][2][4];   // [stage][m][chunk] W rows f32
  float4 avr[2];          // [stage] A row slice

  // ---- stage tile 0 (issued before anything else) ----
  {
    const float* Wp = W + bi0 * 16384;
    #pragma unroll
    for (int m = 0; m < 2; m++) {
      int jm = j0 + m * 16 + r;
      const float* p = Wp + (size_t)jm * 64 + g * 8;
      wreg[0][m][0] = *(const float4*)(p);
      wreg[0][m][1] = *(const float4*)(p + 4);
      wreg[0][m][2] = *(const float4*)(p + 32);
      wreg[0][m][3] = *(const float4*)(p + 36);
    }
    avr[0] = *(const float4*)(A + bi0 * 256 + l * 4);
  }

  // ---- block-invariant loads (shared by all 4 tiles) ----
  short8 x1st[2][2];
  #pragma unroll
  for (int m = 0; m < 2; m++) {
    int jm = j0 + m * 16 + r;
    const unsigned short* q = x1ws + ((size_t)(b * 256 + jm)) * 64 + g * 8;
    x1st[m][0] = *(const short8*)(q);
    x1st[m][1] = *(const short8*)(q + 32);
  }
  float bias1[4], bias2[4];
  #pragma unroll
  for (int n = 0; n < 4; n++) {
    bias1[n] = b_e2e[n * 16 + r];
    bias2[n] = b_e2n[n * 16 + r];
  }

  #pragma unroll
  for (int t = 0; t < 4; t++) {          // fully unrolled: all indices static
    const int s = t & 1;
    const size_t bi = bi0 + t;

    // --- A row -> LDS(ping-pong), abs-sum, adjacency masks ---
    float4 av = avr[s];
    *(float4*)(&Arow[s][w][l * 4]) = av;
    float sum = fabsf(av.x) + fabsf(av.y) + fabsf(av.z) + fabsf(av.w);
    #pragma unroll
    for (int o = 32; o; o >>= 1) sum += __shfl_xor(sum, o, 64);
    const float inv = 1.0f / fmaxf(sum, 1e-12f);
    __builtin_amdgcn_wave_barrier();
    unsigned int msk[2];
    #pragma unroll
    for (int m = 0; m < 2; m++)
      msk[m] = (Arow[s][w][j0 + m * 16 + r] != 0.0f) ? 0xFFFFFFFFu : 0u;

    // --- convert W-part fragments (wreg[s] dies here) ---
    short8 afW[2][2];
    #pragma unroll
    for (int m = 0; m < 2; m++) {
      afW[m][0] = cvt8(wreg[s][m][0], wreg[s][m][1]);
      afW[m][1] = cvt8(wreg[s][m][2], wreg[s][m][3]);
    }

    // --- PREFETCH tile t+1 into wreg[s^1]: in flight under this tile's GEMMs
    if (t + 1 < 4) {
      const float* Wp = W + (bi + 1) * 16384;
      #pragma unroll
      for (int m = 0; m < 2; m++) {
        int jm = j0 + m * 16 + r;
        const float* p = Wp + (size_t)jm * 64 + g * 8;
        wreg[s ^ 1][m][0] = *(const float4*)(p);
        wreg[s ^ 1][m][1] = *(const float4*)(p + 4);
        wreg[s ^ 1][m][2] = *(const float4*)(p + 32);
        wreg[s ^ 1][m][3] = *(const float4*)(p + 36);
      }
      avr[s ^ 1] = *(const float4*)(A + (bi + 1) * 256 + l * 4);
    }

    // --- GEMM1: [32x128]@[128x64] per wave ---
    f32x4 acc[2][4];
    #pragma unroll
    for (int m = 0; m < 2; m++)
      #pragma unroll
      for (int n = 0; n < 4; n++)
        acc[m][n] = (f32x4){0.f, 0.f, 0.f, 0.f};
    #pragma unroll
    for (int ks = 0; ks < 4; ks++) {
      short8 af[2];
      af[0] = (ks < 2) ? afW[0][ks] : mask8(x1st[0][ks - 2], msk[0]);
      af[1] = (ks < 2) ? afW[1][ks] : mask8(x1st[1][ks - 2], msk[1]);
      const unsigned short* bb = wEf + ks * 2048 + l * 8;
      short8 b0 = *(const short8*)(bb);
      short8 b1 = *(const short8*)(bb + 512);
      short8 b2 = *(const short8*)(bb + 1024);
      short8 b3 = *(const short8*)(bb + 1536);
      #pragma unroll
      for (int m = 0; m < 2; m++) {
        acc[m][0] = MFMA(af[m], b0, acc[m][0]);
        acc[m][1] = MFMA(af[m], b1, acc[m][1]);
        acc[m][2] = MFMA(af[m], b2, acc[m][2]);
        acc[m][3] = MFMA(af[m], b3, acc[m][3]);
      }
    }

    // --- epilogue1: bias+relu, NT-store W_new f32, stash bf16 in swizzled LDS
    float* Wout = out + bi * 16384;
    #pragma unroll
    for (int m = 0; m < 2; m++)
      #pragma unroll
      for (int n = 0; n < 4; n++)
        #pragma unroll
        for (int reg = 0; reg < 4; reg++) {
          float v = fmaxf(acc[m][n][reg] + bias1[n], 0.f);
          int row = m * 16 + g * 4 + reg;        // 0..31 within wave tile
          int col = n * 16 + r;
          __builtin_nontemporal_store(v, Wout + (size_t)(j0 + row) * 64 + col);
          int off = row * 128 + col * 2;
          *(unsigned short*)(wnw + (off ^ ((row & 7) << 4))) = (unsigned short)f2bs(v);
        }

    // --- GEMM2: e = relu(W_new @ w_e2n + b): [32x64]@[64x64] per wave ---
    f32x4 acc2[2][4];
    #pragma unroll
    for (int m = 0; m < 2; m++)
      #pragma unroll
      for (int n = 0; n < 4; n++)
        acc2[m][n] = (f32x4){0.f, 0.f, 0.f, 0.f};
    #pragma unroll
    for (int ks = 0; ks < 2; ks++) {
      short8 a2[2];
      #pragma unroll
      for (int m = 0; m < 2; m++) {
        int row = m * 16 + r;
        int off = row * 128 + ks * 64 + g * 16;
        a2[m] = *(const short8*)(wnw + (off ^ ((r & 7) << 4)));
      }
      const unsigned short* bb = wNf + ks * 2048 + l * 8;
      short8 b0 = *(const short8*)(bb);
      short8 b1 = *(const short8*)(bb + 512);
      short8 b2 = *(const short8*)(bb + 1024);
      short8 b3 = *(const short8*)(bb + 1536);
      #pragma unroll
      for (int m = 0; m < 2; m++) {
        acc2[m][0] = MFMA(a2[m], b0, acc2[m][0]);
        acc2[m][1] = MFMA(a2[m], b1, acc2[m][1]);
        acc2[m][2] = MFMA(a2[m], b2, acc2[m][2]);
        acc2[m][3] = MFMA(a2[m], b3, acc2[m][3]);
      }
    }

    // --- epilogue2: bias+relu, x2 partial = sum_j An[j]*e[j][f] (32 rows) ---
    float x2p[4] = {0.f, 0.f, 0.f, 0.f};
    #pragma unroll
    for (int m = 0; m < 2; m++) {
      float An_[4];
      #pragma unroll
      for (int reg = 0; reg < 4; reg++)
        An_[reg] = Arow[s][w][j0 + m * 16 + g * 4 + reg] * inv;
      #pragma unroll
      for (int n = 0; n < 4; n++)
        #pragma unroll
        for (int reg = 0; reg < 4; reg++) {
          float e = fmaxf(acc2[m][n][reg] + bias2[n], 0.f);
          x2p[n] += An_[reg] * e;
        }
    }
    #pragma unroll
    for (int n = 0; n < 4; n++) {
      x2p[n] += __shfl_xor(x2p[n], 16, 64);
      x2p[n] += __shfl_xor(x2p[n], 32, 64);
    }
    if (l < 16) {
      #pragma unroll
      for (int n = 0; n < 4; n++) x2s[t][w][n * 16 + l] = x2p[n];
    }
  }

  __syncthreads();

  // --- fused node update, all 4 tiles: x_new = relu(concat(x,x2)@w_n2n+b) ---
  if (tid < 256) {
    int t = tid >> 6, f = tid & 63;
    size_t bit = bi0 + t;
    float s2 = b_n2n[f];
    const float* xr = x + bit * 64;
    #pragma unroll 8
    for (int k = 0; k < 64; k++) s2 += xr[k] * w_n2n[k * 64 + f];
    #pragma unroll 8
    for (int k = 0; k < 64; k++) {
      float x2k = (x2s[t][0][k] + x2s[t][1][k]) + (x2s[t][2][k] + x2s[t][3][k])
                + (x2s[t][4][k] + x2s[t][5][k]) + (x2s[t][6][k] + x2s[t][7][k]);
      s2 += x2k * w_n2n[(64 + k) * 64 + f];
    }
    __builtin_nontemporal_store(fmaxf(s2, 0.f),
                                out + (size_t)8 * 256 * 256 * 64 + bit * 64 + f);
  }
}

extern "C" void kernel_launch(void* const* d_in, const int* in_sizes, int n_in,
                              void* d_out, int out_size, void* d_ws, size_t ws_size,
                              hipStream_t stream) {
  const float* A     = (const float*)d_in[0];
  const float* W     = (const float*)d_in[1];
  const float* x     = (const float*)d_in[2];
  const float* w_n2e = (const float*)d_in[3];
  const float* b_n2e = (const float*)d_in[4];
  const float* w_e2e = (const float*)d_in[5];
  const float* b_e2e = (const float*)d_in[6];
  const float* w_e2n = (const float*)d_in[7];
  const float* b_e2n = (const float*)d_in[8];
  const float* w_n2n = (const float*)d_in[9];
  const float* b_n2n = (const float*)d_in[10];

  unsigned short* x1ws = (unsigned short*)((char*)d_ws + WS_X1_OFF);
  unsigned short* wEf  = (unsigned short*)((char*)d_ws + WS_WE_OFF);
  unsigned short* wNf  = (unsigned short*)((char*)d_ws + WS_WN_OFF);

  gnn_pre<<<518, 256, 0, stream>>>(x, w_n2e, b_n2e, w_e2e, w_e2n, x1ws, wEf, wNf);
  gnn_main<<<512, 512, 0, stream>>>(A, W, x, b_e2e, b_e2n, w_n2n, b_n2n,
                                    x1ws, wEf, wNf, (float*)d_out);
}